// Round 13
// baseline (168.143 us; speedup 1.0000x reference)
//
#include <hip/hip_runtime.h>

// Problem constants (from reference)
constexpr int B  = 8;
constexpr int T  = 256;
constexpr int U1 = 65;
constexpr int DK = 640;    // D_ENC == D_pred
constexpr int V  = 1024;
constexpr int KTOT = 2 * DK;  // 1280

constexpr int M_ENC  = B * T;    // 2048
constexpr int M_PRED = B * U1;   // 520

typedef float  f32x4  __attribute__((ext_vector_type(4)));
typedef short  short8 __attribute__((ext_vector_type(8)));
typedef unsigned short u16x4 __attribute__((ext_vector_type(4)));

__device__ __forceinline__ short f2bf(float f) {
    union { float f; unsigned u; } x; x.f = f;
    unsigned r = x.u + 0x7fffu + ((x.u >> 16) & 1u);
    return (short)(r >> 16);
}
__device__ __forceinline__ f32x4 bf4_to_f32(u16x4 s) {
    f32x4 o;
    union { unsigned u; float f; } x;
    x.u = ((unsigned)s[0]) << 16; o[0] = x.f;
    x.u = ((unsigned)s[1]) << 16; o[1] = x.f;
    x.u = ((unsigned)s[2]) << 16; o[2] = x.f;
    x.u = ((unsigned)s[3]) << 16; o[3] = x.f;
    return o;
}

// ---------------------------------------------------------------------------
// prep: Wt[v][k]=bf16(W[k][v]); enc_bf=bf16(enc); pred_bf=bf16(pred).
// (frozen from R11/R12)
// ---------------------------------------------------------------------------
constexpr int ENC_ELEM8  = M_ENC * DK / 8;    // 163840
constexpr int PRED_ELEM8 = M_PRED * DK / 8;   // 41600
constexpr int NB_WT   = 40;
constexpr int NB_ENCC = ENC_ELEM8 / 256;      // 640
constexpr int NB_PREDC = (PRED_ELEM8 + 255) / 256;  // 163

__global__ __launch_bounds__(256) void prep_kernel(
    const float* __restrict__ W, const float* __restrict__ enc,
    const float* __restrict__ pred, short* __restrict__ Wt,
    short* __restrict__ enc_bf, short* __restrict__ pred_bf)
{
    const int bid = blockIdx.x;
    const int tid = threadIdx.x;

    if (bid < NB_WT) {
        const int vb = bid & 3;
        const int kb = bid >> 2;
        const int v  = vb * 256 + tid;
        const int k0 = kb * 128;
        for (int k = k0; k < k0 + 128; k += 8) {
            short8 s;
            #pragma unroll
            for (int j = 0; j < 8; ++j)
                s[j] = f2bf(W[(size_t)(k + j) * V + v]);
            *reinterpret_cast<short8*>(Wt + (size_t)v * KTOT + k) = s;
        }
    } else if (bid < NB_WT + NB_ENCC) {
        const int idx  = (bid - NB_WT) * 256 + tid;
        const size_t e = (size_t)idx * 8;
        const f32x4 x = *reinterpret_cast<const f32x4*>(enc + e);
        const f32x4 y = *reinterpret_cast<const f32x4*>(enc + e + 4);
        short8 s;
        s[0]=f2bf(x[0]); s[1]=f2bf(x[1]); s[2]=f2bf(x[2]); s[3]=f2bf(x[3]);
        s[4]=f2bf(y[0]); s[5]=f2bf(y[1]); s[6]=f2bf(y[2]); s[7]=f2bf(y[3]);
        *reinterpret_cast<short8*>(enc_bf + e) = s;
    } else {
        const int idx = (bid - NB_WT - NB_ENCC) * 256 + tid;
        if (idx < PRED_ELEM8) {
            const size_t e = (size_t)idx * 8;
            const f32x4 x = *reinterpret_cast<const f32x4*>(pred + e);
            const f32x4 y = *reinterpret_cast<const f32x4*>(pred + e + 4);
            short8 s;
            s[0]=f2bf(x[0]); s[1]=f2bf(x[1]); s[2]=f2bf(x[2]); s[3]=f2bf(x[3]);
            s[4]=f2bf(y[0]); s[5]=f2bf(y[1]); s[6]=f2bf(y[2]); s[7]=f2bf(y[3]);
            *reinterpret_cast<short8*>(pred_bf + e) = s;
        }
    }
}

// ---------------------------------------------------------------------------
// GEMM: O = bf16(Abf @ Wt[:, kofs:kofs+640] (+bias)).  Pure bf16 MFMA.
// (frozen from R11/R12)
// ---------------------------------------------------------------------------
__global__ __launch_bounds__(256) void gemm_kernel(
    const short* __restrict__ Abf, const short* __restrict__ Wt,
    const float* __restrict__ bias, short* __restrict__ O,
    int M, int kofs)
{
    const int rb   = blockIdx.x >> 4;
    const int cb   = blockIdx.x & 15;
    const int wid  = threadIdx.x >> 6;
    const int lane = threadIdx.x & 63;
    const int wr   = wid >> 1, wc = wid & 1;
    const int m    = lane & 15, g = lane >> 4;

    const int row0 = rb * 64 + wr * 32;
    const int col0 = cb * 64 + wc * 32;

    f32x4 z4; z4[0]=z4[1]=z4[2]=z4[3]=0.f;
    f32x4 acc00 = z4, acc01 = z4, acc10 = z4, acc11 = z4;

    const bool v0 = (row0 + m) < M;
    const bool v1 = (row0 + 16 + m) < M;
    const short* a0p = Abf + (size_t)(row0 + m) * DK;
    const short* a1p = Abf + (size_t)(row0 + 16 + m) * DK;
    const short* b0p = Wt + (size_t)(col0 + m) * KTOT + kofs;
    const short* b1p = Wt + (size_t)(col0 + 16 + m) * KTOT + kofs;

    short8 zero8;
    #pragma unroll
    for (int j = 0; j < 8; ++j) zero8[j] = 0;

    #pragma unroll 2
    for (int kk = 0; kk < DK; kk += 32) {
        const int k0 = kk + g * 8;
        const short8 a0 = v0 ? *reinterpret_cast<const short8*>(a0p + k0) : zero8;
        const short8 a1 = v1 ? *reinterpret_cast<const short8*>(a1p + k0) : zero8;
        const short8 b0 = *reinterpret_cast<const short8*>(b0p + k0);
        const short8 b1 = *reinterpret_cast<const short8*>(b1p + k0);
        acc00 = __builtin_amdgcn_mfma_f32_16x16x32_bf16(a0, b0, acc00, 0, 0, 0);
        acc01 = __builtin_amdgcn_mfma_f32_16x16x32_bf16(a0, b1, acc01, 0, 0, 0);
        acc10 = __builtin_amdgcn_mfma_f32_16x16x32_bf16(a1, b0, acc10, 0, 0, 0);
        acc11 = __builtin_amdgcn_mfma_f32_16x16x32_bf16(a1, b1, acc11, 0, 0, 0);
    }

    #pragma unroll
    for (int nt = 0; nt < 2; ++nt) {
        const int col = col0 + nt * 16 + m;
        const float bv = bias ? bias[col] : 0.f;
        #pragma unroll
        for (int mt = 0; mt < 2; ++mt) {
            const f32x4 a = nt ? (mt ? acc11 : acc01) : (mt ? acc10 : acc00);
            #pragma unroll
            for (int q = 0; q < 4; ++q) {
                const int row = row0 + mt * 16 + g * 4 + q;
                if (row < M)
                    O[(size_t)row * V + col] = f2bf(a[q] + bv);
            }
        }
    }
}

// ---------------------------------------------------------------------------
// bcast: REVERT to R9-proven geometry (1 bt-row per block, 2048 blocks,
// simple unroll-4 u-loop; measured 111.6 us with f32 reads), upgraded to
// bf16 reads. This is simultaneously the likely-win and the attribution
// probe separating R11's bcast-geometry change from its GEMM change.
// ---------------------------------------------------------------------------
__global__ __launch_bounds__(256) void bcast_kernel(
    const short* __restrict__ enc_proj, const short* __restrict__ pred_proj,
    float* __restrict__ out)
{
    const int bt  = blockIdx.x;          // 0..2047
    const int b   = bt >> 8;             // T = 256
    const int tid = threadIdx.x;

    const f32x4 e = bf4_to_f32(*reinterpret_cast<const u16x4*>(
        enc_proj + (size_t)bt * V + tid * 4));

    const short* p = pred_proj + (size_t)b * U1 * V + tid * 4;
    float* o = out + (size_t)bt * U1 * V;

    #pragma unroll 4
    for (int u = 0; u < U1; ++u) {
        const f32x4 pf = bf4_to_f32(
            *reinterpret_cast<const u16x4*>(p + (size_t)u * V));
        *(reinterpret_cast<f32x4*>(o + (size_t)u * V) + tid) = e + pf;
    }
}

extern "C" void kernel_launch(void* const* d_in, const int* in_sizes, int n_in,
                              void* d_out, int out_size, void* d_ws, size_t ws_size,
                              hipStream_t stream)
{
    const float* enc  = (const float*)d_in[0];   // (8,256,640)
    const float* pred = (const float*)d_in[1];   // (8,65,640)
    const float* W    = (const float*)d_in[2];   // (1280,1024)
    const float* bias = (const float*)d_in[3];   // (1024,)
    float* out = (float*)d_out;                  // (8,256,65,1024)

    // ws packing (peak 10.10 MB): [Wt][encbf/pred_proj][pred_bf][enc_proj]
    short* Wt        = (short*)d_ws;                          // V*KTOT
    short* enc_bf    = Wt + (size_t)V * KTOT;                 // M_ENC*DK
    short* pred_bf   = enc_bf + (size_t)M_ENC * DK;           // M_PRED*DK
    short* enc_proj  = pred_bf + (size_t)M_PRED * DK;         // M_ENC*V
    short* pred_proj = enc_bf;                                // M_PRED*V (reuse)

    prep_kernel<<<NB_WT + NB_ENCC + NB_PREDC, 256, 0, stream>>>(
        W, enc, pred, Wt, enc_bf, pred_bf);

    gemm_kernel<<<(M_ENC / 64) * 16, 256, 0, stream>>>(
        enc_bf, Wt, nullptr, enc_proj, M_ENC, 0);

    gemm_kernel<<<((M_PRED + 63) / 64) * 16, 256, 0, stream>>>(
        pred_bf, Wt, bias, pred_proj, M_PRED, DK);

    bcast_kernel<<<M_ENC, 256, 0, stream>>>(enc_proj, pred_proj, out);
}

// Round 14
// 133.036 us; speedup vs baseline: 1.2639x; 1.2639x over previous
//
#include <hip/hip_runtime.h>

// Problem constants (from reference)
constexpr int B  = 8;
constexpr int T  = 256;
constexpr int U1 = 65;
constexpr int DK = 640;    // D_ENC == D_pred
constexpr int V  = 1024;

constexpr int M_ENC  = B * T;    // 2048
constexpr int M_PRED = B * U1;   // 520

constexpr int NKS  = DK / 32;    // 20 k-steps
constexpr int RT_E = M_ENC / 16; // 128 A row-tiles (enc)
constexpr int RT_P = 36;         // pred row-tiles padded (576 rows >= 520)
constexpr int CT   = V / 16;     // 64 B col-tiles

typedef float  f32x4  __attribute__((ext_vector_type(4)));
typedef short  short8 __attribute__((ext_vector_type(8)));
typedef unsigned short u16x4 __attribute__((ext_vector_type(4)));

__device__ __forceinline__ short f2bf(float f) {
    union { float f; unsigned u; } x; x.f = f;
    unsigned r = x.u + 0x7fffu + ((x.u >> 16) & 1u);
    return (short)(r >> 16);
}
__device__ __forceinline__ f32x4 bf4_to_f32(u16x4 s) {
    f32x4 o;
    union { unsigned u; float f; } x;
    x.u = ((unsigned)s[0]) << 16; o[0] = x.f;
    x.u = ((unsigned)s[1]) << 16; o[1] = x.f;
    x.u = ((unsigned)s[2]) << 16; o[2] = x.f;
    x.u = ((unsigned)s[3]) << 16; o[3] = x.f;
    return o;
}

// ---------------------------------------------------------------------------
// prep: emit MFMA-fragment-major packed operands.
//   Apack[(rt*20+ks)*64 + l] (16B) = bf16(A[rt*16+(l&15)][ks*32+(l>>4)*8 ..+8])
//   Bpack[(ct*20+ks)*64 + l] (16B) = bf16(W[kofs+ks*32+(l>>4)*8+j][ct*16+(l&15)])
// GEMM then loads fragments as contiguous 1KB wave-loads (fixes the 16B
// strided-transaction storm diagnosed as X≈56us).
// ---------------------------------------------------------------------------
constexpr int NB_AE = RT_E * NKS * 64 / 256;  // 640 blocks
constexpr int NB_AP = RT_P * NKS * 64 / 256;  // 180
constexpr int NB_BE = CT   * NKS * 64 / 256;  // 320
constexpr int NB_BP = NB_BE;                  // 320

__global__ __launch_bounds__(256) void prep_kernel(
    const float* __restrict__ enc, const float* __restrict__ pred,
    const float* __restrict__ W,
    short* __restrict__ Apack_e, short* __restrict__ Apack_p,
    short* __restrict__ Bpack_e, short* __restrict__ Bpack_p)
{
    const int bid = blockIdx.x;
    const int tid = threadIdx.x;

    if (bid < NB_AE) {                     // ---- A-pack enc ----
        const int chunk = bid * 256 + tid;
        const int l  = chunk & 63;
        const int ks = (chunk >> 6) % NKS;
        const int rt = chunk / (64 * NKS);
        const int row = rt * 16 + (l & 15);
        const float* src = enc + (size_t)row * DK + ks * 32 + (l >> 4) * 8;
        const f32x4 x = *reinterpret_cast<const f32x4*>(src);
        const f32x4 y = *reinterpret_cast<const f32x4*>(src + 4);
        short8 s;
        s[0]=f2bf(x[0]); s[1]=f2bf(x[1]); s[2]=f2bf(x[2]); s[3]=f2bf(x[3]);
        s[4]=f2bf(y[0]); s[5]=f2bf(y[1]); s[6]=f2bf(y[2]); s[7]=f2bf(y[3]);
        *reinterpret_cast<short8*>(Apack_e + (size_t)chunk * 8) = s;
    } else if (bid < NB_AE + NB_AP) {      // ---- A-pack pred (zero-padded) ----
        const int chunk = (bid - NB_AE) * 256 + tid;
        const int l  = chunk & 63;
        const int ks = (chunk >> 6) % NKS;
        const int rt = chunk / (64 * NKS);
        const int row = rt * 16 + (l & 15);
        short8 s;
        if (row < M_PRED) {
            const float* src = pred + (size_t)row * DK + ks * 32 + (l >> 4) * 8;
            const f32x4 x = *reinterpret_cast<const f32x4*>(src);
            const f32x4 y = *reinterpret_cast<const f32x4*>(src + 4);
            s[0]=f2bf(x[0]); s[1]=f2bf(x[1]); s[2]=f2bf(x[2]); s[3]=f2bf(x[3]);
            s[4]=f2bf(y[0]); s[5]=f2bf(y[1]); s[6]=f2bf(y[2]); s[7]=f2bf(y[3]);
        } else {
            #pragma unroll
            for (int j = 0; j < 8; ++j) s[j] = 0;
        }
        *reinterpret_cast<short8*>(Apack_p + (size_t)chunk * 8) = s;
    } else {                               // ---- B-pack enc / pred ----
        const bool isE = (bid < NB_AE + NB_AP + NB_BE);
        const int  base = isE ? (NB_AE + NB_AP) : (NB_AE + NB_AP + NB_BE);
        short* Bp = isE ? Bpack_e : Bpack_p;
        const int kofs = isE ? 0 : DK;
        const int chunk = (bid - base) * 256 + tid;
        const int l  = chunk & 63;
        const int ks = (chunk >> 6) % NKS;
        const int ct = chunk / (64 * NKS);
        const int v  = ct * 16 + (l & 15);
        const int k0 = kofs + ks * 32 + (l >> 4) * 8;
        short8 s;
        #pragma unroll
        for (int j = 0; j < 8; ++j)
            s[j] = f2bf(W[(size_t)(k0 + j) * V + v]);
        *reinterpret_cast<short8*>(Bp + (size_t)chunk * 8) = s;
    }
}

// ---------------------------------------------------------------------------
// GEMM (both problems in one launch): O = bf16(A @ Wpart (+bias)).
// Block = 256 thr (4 waves 2x2), block tile 64x64, wave tile 32x32.
// All fragment loads coalesced 1KB wave-loads from packed buffers.
// Grid: 512 enc blocks + 144 pred blocks.
// ---------------------------------------------------------------------------
constexpr int NB_GE = (M_ENC / 64) * 16;     // 512
constexpr int NB_GP = (RT_P / 4) * 16;       // 144

__global__ __launch_bounds__(256) void gemm_kernel(
    const short* __restrict__ Apack_e, const short* __restrict__ Apack_p,
    const short* __restrict__ Bpack_e, const short* __restrict__ Bpack_p,
    const float* __restrict__ bias,
    short* __restrict__ enc_proj, short* __restrict__ pred_proj)
{
    const bool isE = (blockIdx.x < NB_GE);
    const int  lb  = isE ? blockIdx.x : blockIdx.x - NB_GE;
    const int  rb  = lb >> 4;
    const int  cb  = lb & 15;

    const short* Ap = isE ? Apack_e : Apack_p;
    const short* Bp = isE ? Bpack_e : Bpack_p;
    short* O        = isE ? enc_proj : pred_proj;
    const int M     = isE ? M_ENC : M_PRED;

    const int wid  = threadIdx.x >> 6;
    const int lane = threadIdx.x & 63;
    const int wr   = wid >> 1, wc = wid & 1;
    const int m    = lane & 15, g = lane >> 4;

    const int rt0 = rb * 4 + wr * 2;        // this wave's 2 row-tiles
    const int ct0 = cb * 4 + wc * 2;        // this wave's 2 col-tiles

    // fragment streams: (tile*20 + ks)*64 lanes * 8 shorts
    const short* a0p = Ap + ((size_t)rt0 * NKS) * 512 + lane * 8;
    const short* a1p = a0p + (size_t)NKS * 512;
    const short* b0p = Bp + ((size_t)ct0 * NKS) * 512 + lane * 8;
    const short* b1p = b0p + (size_t)NKS * 512;

    f32x4 z4; z4[0]=z4[1]=z4[2]=z4[3]=0.f;
    f32x4 acc00 = z4, acc01 = z4, acc10 = z4, acc11 = z4;

    #pragma unroll 4
    for (int ks = 0; ks < NKS; ++ks) {
        const size_t o = (size_t)ks * 512;
        const short8 a0 = *reinterpret_cast<const short8*>(a0p + o);
        const short8 a1 = *reinterpret_cast<const short8*>(a1p + o);
        const short8 b0 = *reinterpret_cast<const short8*>(b0p + o);
        const short8 b1 = *reinterpret_cast<const short8*>(b1p + o);
        acc00 = __builtin_amdgcn_mfma_f32_16x16x32_bf16(a0, b0, acc00, 0, 0, 0);
        acc01 = __builtin_amdgcn_mfma_f32_16x16x32_bf16(a0, b1, acc01, 0, 0, 0);
        acc10 = __builtin_amdgcn_mfma_f32_16x16x32_bf16(a1, b0, acc10, 0, 0, 0);
        acc11 = __builtin_amdgcn_mfma_f32_16x16x32_bf16(a1, b1, acc11, 0, 0, 0);
    }

    #pragma unroll
    for (int nt = 0; nt < 2; ++nt) {
        const int col = (ct0 + nt) * 16 + m;
        const float bv = isE ? 0.f : bias[col];
        #pragma unroll
        for (int mt = 0; mt < 2; ++mt) {
            const f32x4 a = nt ? (mt ? acc11 : acc01) : (mt ? acc10 : acc00);
            #pragma unroll
            for (int q = 0; q < 4; ++q) {
                const int row = (rt0 + mt) * 16 + g * 4 + q;
                if (row < M)
                    O[(size_t)row * V + col] = f2bf(a[q] + bv);
            }
        }
    }
}

// ---------------------------------------------------------------------------
// bcast (FROZEN from R12 — best measured): 2 bt-rows/block, 1024 blocks,
// 8-deep p-load batches, temporal stores, bf16 reads, f32 out.
// ---------------------------------------------------------------------------
__global__ __launch_bounds__(256) void bcast_kernel(
    const short* __restrict__ enc_proj, const short* __restrict__ pred_proj,
    float* __restrict__ out)
{
    const int bt0 = blockIdx.x * 2;
    const int b   = bt0 >> 8;            // T = 256
    const int tid = threadIdx.x;

    const f32x4 e0 = bf4_to_f32(*reinterpret_cast<const u16x4*>(
        enc_proj + (size_t)bt0 * V + tid * 4));
    const f32x4 e1 = bf4_to_f32(*reinterpret_cast<const u16x4*>(
        enc_proj + (size_t)(bt0 + 1) * V + tid * 4));

    const short* p = pred_proj + (size_t)b * U1 * V + tid * 4;
    float* o0 = out + (size_t)bt0 * U1 * V;
    float* o1 = out + (size_t)(bt0 + 1) * U1 * V;

    for (int u0 = 0; u0 < 64; u0 += 8) {
        u16x4 pv[8];
        #pragma unroll
        for (int j = 0; j < 8; ++j)
            pv[j] = *reinterpret_cast<const u16x4*>(p + (size_t)(u0 + j) * V);
        #pragma unroll
        for (int j = 0; j < 8; ++j) {
            const f32x4 pf = bf4_to_f32(pv[j]);
            *(reinterpret_cast<f32x4*>(o0 + (size_t)(u0 + j) * V) + tid) = e0 + pf;
            *(reinterpret_cast<f32x4*>(o1 + (size_t)(u0 + j) * V) + tid) = e1 + pf;
        }
    }
    {   // tail u = 64
        const f32x4 pf = bf4_to_f32(
            *reinterpret_cast<const u16x4*>(p + (size_t)64 * V));
        *(reinterpret_cast<f32x4*>(o0 + (size_t)64 * V) + tid) = e0 + pf;
        *(reinterpret_cast<f32x4*>(o1 + (size_t)64 * V) + tid) = e1 + pf;
    }
}

extern "C" void kernel_launch(void* const* d_in, const int* in_sizes, int n_in,
                              void* d_out, int out_size, void* d_ws, size_t ws_size,
                              hipStream_t stream)
{
    const float* enc  = (const float*)d_in[0];   // (8,256,640)
    const float* pred = (const float*)d_in[1];   // (8,65,640)
    const float* W    = (const float*)d_in[2];   // (1280,1024)
    const float* bias = (const float*)d_in[3];   // (1024,)
    float* out = (float*)d_out;                  // (8,256,65,1024)

    // ws layout in shorts (10.17 MB total, fits proven 10.5 MB):
    //   [Apack_e 2.62MB][Apack_p 0.74MB][Bpack_e 1.31MB][Bpack_p 1.31MB][enc_proj 4.19MB]
    // pred_proj (0.53MB) overlays Apack_e (dead after enc-GEMM... written by
    // pred-GEMM which runs in the same launch AFTER-in-stream; block order
    // within one launch is fine since enc blocks read Apack_e and pred blocks
    // write pred_proj -> ALIAS HAZARD. Keep pred_proj on Apack_p instead:
    // Apack_p is read by pred blocks of the SAME gemm launch -> also hazard.
    // => give pred_proj its own slot; total 10.70MB... trim by overlaying on
    // Bpack region is same-launch too. SAFE choice: separate slot, 10.70 MB
    // still < R2-proven 10.52? No. => run pred GEMM as the same kernel but
    // keep pred_proj in enc_proj tail: enc_proj is written by enc blocks of
    // the same launch at rows < 2048; pred_proj needs 520*1024 shorts; place
    // it AFTER enc_proj: total = 10.17 + 0.53 = 10.70MB > 10.52 proven.
    // Final resolution: overlay pred_proj on Apack_e but split the GEMM into
    // two launches (enc, then pred) - stream-serialized, no alias hazard.
    short* Apack_e  = (short*)d_ws;                                   // 1,310,720
    short* Apack_p  = Apack_e + (size_t)RT_E * NKS * 512;             //   368,640
    short* Bpack_e  = Apack_p + (size_t)RT_P * NKS * 512;             //   655,360
    short* Bpack_p  = Bpack_e + (size_t)CT * NKS * 512;               //   655,360
    short* enc_proj = Bpack_p + (size_t)CT * NKS * 512;               // 2,097,152
    short* pred_proj = Apack_e;                                       // overlay (enc-GEMM dead)

    prep_kernel<<<NB_AE + NB_AP + NB_BE + NB_BP, 256, 0, stream>>>(
        enc, pred, W, Apack_e, Apack_p, Bpack_e, Bpack_p);

    // enc GEMM launch (blocks [0, NB_GE) take the isE path)
    gemm_kernel<<<NB_GE, 256, 0, stream>>>(
        Apack_e, Apack_p, Bpack_e, Bpack_p, bias, enc_proj, pred_proj);

    // pred GEMM launch: pass Apack_p/Bpack_p as the "enc" slot disabled by
    // launching exactly the pred block range via an offset grid. Simplest:
    // launch NB_GE+NB_GP blocks would redo enc; instead launch a grid of
    // NB_GP blocks with isE forced false by biasing blockIdx: use a second
    // kernel instance where NB_GE=0 is emulated via template-free trick:
    // we just launch NB_GP blocks and rely on isE = (blockIdx.x < NB_GE)
    // being false only for x >= 512 - so add 512 dummy? No. Use separate
    // entry: gemm_pred_kernel below.
    // (see gemm_pred_kernel)
    extern __global__ void gemm_pred_kernel(
        const short*, const short*, const float*, short*);
    gemm_pred_kernel<<<NB_GP, 256, 0, stream>>>(Apack_p, Bpack_p, bias, pred_proj);

    bcast_kernel<<<M_ENC / 2, 256, 0, stream>>>(enc_proj, pred_proj, out);
}

// ---------------------------------------------------------------------------
// pred GEMM as its own launch (runs after enc GEMM -> Apack_e overlay safe)
// ---------------------------------------------------------------------------
__global__ __launch_bounds__(256) void gemm_pred_kernel(
    const short* __restrict__ Apack_p, const short* __restrict__ Bpack_p,
    const float* __restrict__ bias, short* __restrict__ pred_proj)
{
    const int rb = blockIdx.x >> 4;
    const int cb = blockIdx.x & 15;

    const int wid  = threadIdx.x >> 6;
    const int lane = threadIdx.x & 63;
    const int wr   = wid >> 1, wc = wid & 1;
    const int m    = lane & 15, g = lane >> 4;

    const int rt0 = rb * 4 + wr * 2;
    const int ct0 = cb * 4 + wc * 2;

    const short* a0p = Apack_p + ((size_t)rt0 * NKS) * 512 + lane * 8;
    const short* a1p = a0p + (size_t)NKS * 512;
    const short* b0p = Bpack_p + ((size_t)ct0 * NKS) * 512 + lane * 8;
    const short* b1p = b0p + (size_t)NKS * 512;

    f32x4 z4; z4[0]=z4[1]=z4[2]=z4[3]=0.f;
    f32x4 acc00 = z4, acc01 = z4, acc10 = z4, acc11 = z4;

    #pragma unroll 4
    for (int ks = 0; ks < NKS; ++ks) {
        const size_t o = (size_t)ks * 512;
        const short8 a0 = *reinterpret_cast<const short8*>(a0p + o);
        const short8 a1 = *reinterpret_cast<const short8*>(a1p + o);
        const short8 b0 = *reinterpret_cast<const short8*>(b0p + o);
        const short8 b1 = *reinterpret_cast<const short8*>(b1p + o);
        acc00 = __builtin_amdgcn_mfma_f32_16x16x32_bf16(a0, b0, acc00, 0, 0, 0);
        acc01 = __builtin_amdgcn_mfma_f32_16x16x32_bf16(a0, b1, acc01, 0, 0, 0);
        acc10 = __builtin_amdgcn_mfma_f32_16x16x32_bf16(a1, b0, acc10, 0, 0, 0);
        acc11 = __builtin_amdgcn_mfma_f32_16x16x32_bf16(a1, b1, acc11, 0, 0, 0);
    }

    #pragma unroll
    for (int nt = 0; nt < 2; ++nt) {
        const int col = (ct0 + nt) * 16 + m;
        const float bv = bias[col];
        #pragma unroll
        for (int mt = 0; mt < 2; ++mt) {
            const f32x4 a = nt ? (mt ? acc11 : acc01) : (mt ? acc10 : acc00);
            #pragma unroll
            for (int q = 0; q < 4; ++q) {
                const int row = (rt0 + mt) * 16 + g * 4 + q;
                if (row < M_PRED)
                    pred_proj[(size_t)row * V + col] = f2bf(a[q] + bv);
            }
        }
    }
}